// Round 2
// baseline (992.649 us; speedup 1.0000x reference)
//
#include <hip/hip_runtime.h>

#define KTAGS 64
#define START_TAG 1
#define END_TAG 2
#define NEGV -10000.0f
#define MAXT 512

// One block (1 wave, 64 lanes) per sequence. Lane j owns tag j.
// Forward: out_new[j] = max_i(((trans[i][j]+feat[t][j])+end_adj)+out[i]),
// computed in the reference's exact float-add order so argmax matches bitwise.
// Backpointers in LDS (uint8), backtrace by lane 0, padded tag row written by all lanes.
__global__ __launch_bounds__(64) void crf_viterbi(
    const float* __restrict__ feats, const int* __restrict__ leng,
    const float* __restrict__ trans, float* __restrict__ out_tags,
    float* __restrict__ out_scores, int T) {
  const int b = blockIdx.x;
  const int j = threadIdx.x;

  __shared__ float s_out[KTAGS];
  __shared__ unsigned char s_bp[MAXT * KTAGS];
  __shared__ short s_tags[MAXT];

  const int L = leng[b];

  // Per-lane copy of trans column j (64 VGPRs); coalesced loads (per i, lanes read a row).
  float tc[KTAGS];
#pragma unroll
  for (int i = 0; i < KTAGS; ++i) tc[i] = trans[i * KTAGS + j];

  float outj = (j == START_TAG) ? 0.0f : NEGV;
  s_out[j] = outj;
  __syncthreads();

  const float* fb = feats + (size_t)b * T * KTAGS;

  for (int t = 1; t < L; ++t) {
    const float feat = fb[t * KTAGS + j];
    float best;
    int bi = 0;
    if (t == L - 1) {
      // last valid step: add end_adj[j] = (j==END ? 0 : NEG) between (trans+feat) and (+out)
      const float e = (j == END_TAG) ? 0.0f : NEGV;
      float u0 = tc[0] + feat;
      u0 = u0 + e;
      best = u0 + s_out[0];
#pragma unroll
      for (int i = 1; i < KTAGS; ++i) {
        float u = tc[i] + feat;
        u = u + e;
        const float cand = u + s_out[i];
        if (cand > best) { best = cand; bi = i; }  // strict >: first-index tie-break like jnp.argmax
      }
    } else {
      float u0 = tc[0] + feat;
      best = u0 + s_out[0];
#pragma unroll
      for (int i = 1; i < KTAGS; ++i) {
        const float u = tc[i] + feat;
        const float cand = u + s_out[i];
        if (cand > best) { best = cand; bi = i; }
      }
    }
    __syncthreads();  // everyone done reading s_out
    outj = best;
    s_out[j] = outj;
    s_bp[t * KTAGS + j] = (unsigned char)bi;
    __syncthreads();  // s_out updated for next step
  }

  // Cross-lane argmax of final out (first index wins on ties), result in all lanes.
  float v = outj;
  int idx = j;
#pragma unroll
  for (int d = 1; d < 64; d <<= 1) {
    const float ov = __shfl_xor(v, d, 64);
    const int oi = __shfl_xor(idx, d, 64);
    if (ov > v || (ov == v && oi < idx)) { v = ov; idx = oi; }
  }

  // Backtrace (serial dependent chain) by lane 0.
  if (j == 0) {
    int tag = idx;
    s_tags[L - 1] = (short)tag;
    for (int t = L - 2; t >= 0; --t) {
      tag = s_bp[(t + 1) * KTAGS + tag];
      s_tags[t] = (short)tag;
    }
  }
  __syncthreads();

  // Write zero-padded tag row (as float32 values) + score.
  for (int t = j; t < T; t += 64) {
    out_tags[(size_t)b * T + t] = (t < L) ? (float)s_tags[t] : 0.0f;
  }
  if (j == 0) out_scores[b] = v;
}

extern "C" void kernel_launch(void* const* d_in, const int* in_sizes, int n_in,
                              void* d_out, int out_size, void* d_ws, size_t ws_size,
                              hipStream_t stream) {
  const float* feats = (const float*)d_in[0];
  const int* leng = (const int*)d_in[1];
  const float* trans = (const float*)d_in[2];
  const int B = in_sizes[1];
  const int T = in_sizes[0] / (B * KTAGS);  // 512

  float* out_tags = (float*)d_out;
  float* out_scores = out_tags + (size_t)B * T;

  crf_viterbi<<<B, 64, 0, stream>>>(feats, leng, trans, out_tags, out_scores, T);
}

// Round 3
// 660.384 us; speedup vs baseline: 1.5031x; 1.5031x over previous
//
#include <hip/hip_runtime.h>

#define KTAGS 64
#define START_TAG 1
#define END_TAG 2
#define NEGV -10000.0f
#define MAXT 512

// Broadcast lane i's register value to all lanes (no LDS, no barrier).
__device__ __forceinline__ float rl(float x, int i) {
  return __int_as_float(__builtin_amdgcn_readlane(__float_as_int(x), i));
}

// One Viterbi step for destination tag j (= lane): argmax_i ((tc[i]+feat)[+e]) + out[i].
// Exact float-add order of the reference; tree merge is exact because max +
// first-index tie-break over a fixed candidate set is order-independent
// (every merge takes the higher-index side only on strict >).
template<bool END>
__device__ __forceinline__ void step64(const float* tc, float feat, float e,
                                       float outj, float& best, int& besti) {
  float gv[8]; int gi[8];
#pragma unroll
  for (int g = 0; g < 8; ++g) {
    float c[8];
#pragma unroll
    for (int k = 0; k < 8; ++k) {
      const int i = g * 8 + k;
      float u = tc[i] + feat;
      if (END) u = u + e;
      c[k] = u + rl(outj, i);
    }
    float va = c[0]; int ia = 0;
    if (c[1] > va) { va = c[1]; ia = 1; }
    float vb = c[2]; int ib = 2;
    if (c[3] > vb) { vb = c[3]; ib = 3; }
    float vc = c[4]; int ic = 4;
    if (c[5] > vc) { vc = c[5]; ic = 5; }
    float vd = c[6]; int id = 6;
    if (c[7] > vd) { vd = c[7]; id = 7; }
    if (vb > va) { va = vb; ia = ib; }
    if (vd > vc) { vc = vd; ic = id; }
    if (vc > va) { va = vc; ia = ic; }
    gv[g] = va; gi[g] = g * 8 + ia;
  }
  if (gv[1] > gv[0]) { gv[0] = gv[1]; gi[0] = gi[1]; }
  if (gv[3] > gv[2]) { gv[2] = gv[3]; gi[2] = gi[3]; }
  if (gv[5] > gv[4]) { gv[4] = gv[5]; gi[4] = gi[5]; }
  if (gv[7] > gv[6]) { gv[6] = gv[7]; gi[6] = gi[7]; }
  if (gv[2] > gv[0]) { gv[0] = gv[2]; gi[0] = gi[2]; }
  if (gv[6] > gv[4]) { gv[4] = gv[6]; gi[4] = gi[6]; }
  if (gv[4] > gv[0]) { gv[0] = gv[4]; gi[0] = gi[4]; }
  best = gv[0]; besti = gi[0];
}

// One block = one wave = one sequence; lane j owns destination tag j.
__global__ __launch_bounds__(64) void crf_viterbi(
    const float* __restrict__ feats, const int* __restrict__ leng,
    const float* __restrict__ trans, float* __restrict__ out_tags,
    float* __restrict__ out_scores, int T) {
  const int b = blockIdx.x;
  const int j = threadIdx.x;

  __shared__ unsigned char s_bp[MAXT * KTAGS];
  __shared__ short s_tags[MAXT];

  const int L = leng[b];

  // trans column j in VGPRs (loads coalesced per row i).
  float tc[KTAGS];
#pragma unroll
  for (int i = 0; i < KTAGS; ++i) tc[i] = trans[i * KTAGS + j];

  float outj = (j == START_TAG) ? 0.0f : NEGV;

  const float* fp = feats + (size_t)b * T * KTAGS + j;

  // Prefetch feat for t=1.
  float feat_next = (L > 1) ? fp[1 * KTAGS] : 0.0f;

  for (int t = 1; t < L - 1; ++t) {
    const float feat = feat_next;
    feat_next = fp[(t + 1) * KTAGS];  // prefetch next step (hides HBM/L2 latency)
    float best; int bi;
    step64<false>(tc, feat, 0.0f, outj, best, bi);
    s_bp[t * KTAGS + j] = (unsigned char)bi;
    outj = best;
  }
  if (L > 1) {  // last valid step: end_adj inserted between (trans+feat) and (+out)
    const float e = (j == END_TAG) ? 0.0f : NEGV;
    float best; int bi;
    step64<true>(tc, feat_next, e, outj, best, bi);
    s_bp[(L - 1) * KTAGS + j] = (unsigned char)bi;
    outj = best;
  }

  // Cross-lane argmax of final scores (first index wins ties), result uniform.
  float v = outj;
  int idx = j;
#pragma unroll
  for (int d = 1; d < 64; d <<= 1) {
    const float ov = __shfl_xor(v, d, 64);
    const int oi = __shfl_xor(idx, d, 64);
    if (ov > v || (ov == v && oi < idx)) { v = ov; idx = oi; }
  }

  __syncthreads();  // bp writes visible before backtrace reads

  // Pipelined backtrace: wave-wide row load (address depends only on t),
  // dependent chain is just readlane (uniform tag).
  int tag = idx;
  if (j == 0) s_tags[L - 1] = (short)tag;
  int row = (L > 1) ? (int)s_bp[(L - 1) * KTAGS + j] : 0;
  for (int t = L - 2; t >= 0; --t) {
    const int row_next = (t > 0) ? (int)s_bp[t * KTAGS + j] : 0;
    tag = __builtin_amdgcn_readlane(row, tag);
    if (j == 0) s_tags[t] = (short)tag;
    row = row_next;
  }
  __syncthreads();

  // Zero-padded tag row (float32 values) + score.
  for (int t = j; t < T; t += 64) {
    out_tags[(size_t)b * T + t] = (t < L) ? (float)s_tags[t] : 0.0f;
  }
  if (j == 0) out_scores[b] = v;
}

extern "C" void kernel_launch(void* const* d_in, const int* in_sizes, int n_in,
                              void* d_out, int out_size, void* d_ws, size_t ws_size,
                              hipStream_t stream) {
  const float* feats = (const float*)d_in[0];
  const int* leng = (const int*)d_in[1];
  const float* trans = (const float*)d_in[2];
  const int B = in_sizes[1];
  const int T = in_sizes[0] / (B * KTAGS);  // 512

  float* out_tags = (float*)d_out;
  float* out_scores = out_tags + (size_t)B * T;

  crf_viterbi<<<B, 64, 0, stream>>>(feats, leng, trans, out_tags, out_scores, T);
}